// Round 13
// baseline (4583.719 us; speedup 1.0000x reference)
//
#include <hip/hip_runtime.h>
#include <hip/hip_bf16.h>
#include <hip/hip_cooperative_groups.h>

#define BATCH 8
#define TSEQ 8
#define HH 64
#define WW 64
#define HID 64
#define PT 10   // T + NUM_NODE - 1
#define PIXN 32768   // BATCH*HH*WW

typedef __bf16 bf16_t;
typedef __bf16 bf16x8 __attribute__((ext_vector_type(8)));
typedef float  f32x4  __attribute__((ext_vector_type(4)));

__device__ __forceinline__ float fsigmoid(float v) {
    float e = __builtin_amdgcn_exp2f(-1.4426950408889634f * v);
    return __builtin_amdgcn_rcpf(1.0f + e);
}
__device__ __forceinline__ float ftanh(float v) {
    float e = __builtin_amdgcn_exp2f(2.8853900817779268f * v);   // e^(2v)
    return 1.0f - 2.0f * __builtin_amdgcn_rcpf(1.0f + e);
}

// ---------------------------------------------------------------------------
// Weight pack for 16x16x32 MFMA B-fragments (R10):
//   dst[((chunk*NT16 + nt)*64 + lane)*8 + j],  chunk = tap*KC + kc  (KC=CinPad/32)
//     = w[co = nt*16 + (lane&15)][ci = kc*32 + (lane>>4)*8 + j][tap]
// ---------------------------------------------------------------------------
struct PackSeg { const float* src; bf16_t* dst; int NT16; int KC; int CinReal; int begin; };
struct PackArgs { PackSeg s[12]; int total; };

__global__ void wpack_all(PackArgs P) {
    int idx = blockIdx.x * 256 + threadIdx.x;
    if (idx >= P.total) return;
    int si = 0;
#pragma unroll
    for (int i = 1; i < 12; ++i) if (idx >= P.s[i].begin) si = i;
    PackSeg sg = P.s[si];
    int l = idx - sg.begin;
    int j    = l & 7;
    int lane = (l >> 3) & 63;
    int rest = l >> 9;
    int nt   = rest % sg.NT16;
    int chunk = rest / sg.NT16;
    int kc  = chunk % sg.KC;
    int tap = chunk / sg.KC;
    int co = nt * 16 + (lane & 15);
    int ci = kc * 32 + (lane >> 4) * 8 + j;
    float v = (ci < sg.CinReal) ? sg.src[((long)co * sg.CinReal + ci) * 9 + tap] : 0.0f;
    sg.dst[l] = (bf16_t)v;
}

// x (B,T,3,H,W) fp32 -> xb [t][b][y][x][64] bf16 (channels 3..63 zero)
__global__ void xcvt_k(const float* __restrict__ x, bf16_t* __restrict__ xb) {
    int idx = blockIdx.x * 256 + threadIdx.x;
    if (idx >= 8 * 8 * 64 * 64 * 64) return;
    int c  = idx & 63;
    int xx = (idx >> 6) & 63;
    int y  = (idx >> 12) & 63;
    int b  = (idx >> 18) & 7;
    int t  = idx >> 21;
    float v = 0.0f;
    if (c < 3) v = x[((((long)b * TSEQ + t) * 3 + c) * 64 + y) * 64 + xx];
    xb[idx] = (bf16_t)v;
}

// h fp32 NHWC -> NCHW fp32 out
__global__ void hout_k(const float* __restrict__ hf, float* __restrict__ out) {
    int idx = blockIdx.x * 256 + threadIdx.x;
    if (idx >= 8 * 64 * 64 * 64) return;
    int xx = idx & 63;
    int y  = (idx >> 6) & 63;
    int c  = (idx >> 12) & 63;
    int b  = idx >> 18;
    out[idx] = hf[((((long)b * 64 + y) * 64 + xx) * 64) + c];
}

// ---------------------------------------------------------------------------
// Shared conv stage (R12 body, bit-identical math).
// vbx in [0,256): b = vbx&7 (XCD-pinned), y0 = (vbx>>3)*2 (2 output rows).
// MODE 0: plain conv -> bf16 NHWC.  MODE 1: gates -> rh bf16 + z f32.
// MODE 2: cand -> h fp32 + h bf16 (GRU update).
// Epilogue bounces outputs through LDS for coalesced 128-B global stores.
// ---------------------------------------------------------------------------
struct NP {
    const bf16_t* A0;
    const bf16_t* A1;
    const float*  Zf;
    const float*  Hf;
    const bf16_t* Hb;
    const bf16_t* Wp;
    const float*  bias;
    bf16_t* outB;
    float*  outF;
};
struct NPs { NP n[3]; };

template <int CIN0, int CIN1, int COUT, int MODE>
__device__ __forceinline__ void conv_stage(char* __restrict__ smem, const NP np,
                                           int vbx, int tid)
{
    constexpr int CIN  = CIN0 + CIN1;
    constexpr int NT16 = COUT / 16;
    constexpr int NCH  = CIN / 8;
    constexpr int KC   = CIN / 32;
    constexpr int NCHUNK = 9 * KC;
    constexpr int PSB  = CIN * 2 + 8;
    constexpr int NT_W = (NT16 > 4) ? NT16 / 4 : 1;
    constexpr int NW_N = NT16 / NT_W;
    constexpr int NW_M = 4 / NW_N;
    constexpr int MT_W = 8 / NW_M;
    constexpr int PF   = 4;
    constexpr int OSB  = COUT + 8;

    const int lane = tid & 63;
    const int w    = tid >> 6;
    const int b  = vbx & 7;
    const int y0 = (vbx >> 3) * 2;

    const int nt0 = (w % NW_N) * NT_W;
    const int mt0 = (w / NW_N) * MT_W;
    const int l15 = lane & 15;
    const int kg  = lane >> 4;

    // ---- B-fragment ring: prologue loads before staging ----
    const bf16_t* wp0 = np.Wp + (size_t)nt0 * 512 + (size_t)lane * 8;
    bf16x8 ring[PF][NT_W];
#pragma unroll
    for (int i = 0; i < PF; ++i)
#pragma unroll
        for (int ni = 0; ni < NT_W; ++ni)
            ring[i][ni] = *(const bf16x8*)(wp0 + (size_t)i * (NT16 * 512) + ni * 512);

    // ---- stage 4 rows x 66 px x CIN into padded LDS ----
    for (int c = tid; c < 4 * 66 * NCH; c += 256) {
        int ry = c / (66 * NCH);
        int r  = c - ry * 66 * NCH;
        int px = r / NCH;
        int c2 = r - px * NCH;
        int gy = y0 + ry - 1, gx = px - 1;
        bf16x8 v = {};
        if ((unsigned)gy < 64u && (unsigned)gx < 64u) {
            long pix = ((long)b * 64 + gy) * 64 + gx;
            int ci = c2 * 8;
            if (CIN1 == 0 || ci < CIN0) v = *(const bf16x8*)(np.A0 + pix * CIN0 + ci);
            else                        v = *(const bf16x8*)(np.A1 + pix * CIN1 + (ci - CIN0));
        }
        *(bf16x8*)(smem + (ry * 66 + px) * PSB + c2 * 16) = v;
    }
    __syncthreads();

    int ab[3];
#pragma unroll
    for (int kx = 0; kx < 3; ++kx)
        ab[kx] = (l15 + kx) * PSB + kg * 16;

    f32x4 acc[MT_W][NT_W];
#pragma unroll
    for (int mi = 0; mi < MT_W; ++mi)
#pragma unroll
        for (int ni = 0; ni < NT_W; ++ni) {
            float bv = np.bias[(nt0 + ni) * 16 + l15];
            acc[mi][ni] = (f32x4){bv, bv, bv, bv};
        }

#pragma unroll
    for (int ch = 0; ch < NCHUNK; ++ch) {
        const int tap = ch / KC, kc = ch % KC;
        const int ky = tap / 3, kx = tap % 3;
        bf16x8 bcur[NT_W];
#pragma unroll
        for (int ni = 0; ni < NT_W; ++ni) bcur[ni] = ring[ch % PF][ni];
        if (ch + PF < NCHUNK) {
#pragma unroll
            for (int ni = 0; ni < NT_W; ++ni)
                ring[ch % PF][ni] =
                    *(const bf16x8*)(wp0 + (size_t)(ch + PF) * (NT16 * 512) + ni * 512);
        }
#pragma unroll
        for (int mi = 0; mi < MT_W; ++mi) {
            const int mt = mt0 + mi;
            const int row = mt >> 2, xseg = mt & 3;
            const int imm = (row + ky) * (66 * PSB) + xseg * (16 * PSB) + kc * 64;
            bf16x8 a = *(const bf16x8*)(smem + ab[kx] + imm);
#pragma unroll
            for (int ni = 0; ni < NT_W; ++ni)
                acc[mi][ni] = __builtin_amdgcn_mfma_f32_16x16x32_bf16(
                    a, bcur[ni], acc[mi][ni], 0, 0, 0);
        }
    }

    // ---- epilogue: LDS-bounce for coalesced global stores ----
    __syncthreads();
    const long pixbase = ((long)b * 64 + y0) * 64;   // 128 contiguous pixels

    if (MODE == 0) {
        bf16_t* so = (bf16_t*)smem;                  // [128][OSB]
#pragma unroll
        for (int mi = 0; mi < MT_W; ++mi) {
            const int mt = mt0 + mi;
            const int lpx0 = (mt >> 2) * 64 + (mt & 3) * 16 + kg * 4;
#pragma unroll
            for (int ni = 0; ni < NT_W; ++ni) {
                const int co = (nt0 + ni) * 16 + l15;
#pragma unroll
                for (int reg = 0; reg < 4; ++reg)
                    so[(lpx0 + reg) * OSB + co] = (bf16_t)acc[mi][ni][reg];
            }
        }
        __syncthreads();
        for (int i = tid; i < 128 * (COUT / 8); i += 256) {
            const int p = i / (COUT / 8);
            const int cc = (i % (COUT / 8)) * 8;
            *(bf16x8*)(np.outB + (pixbase + p) * COUT + cc) =
                *(const bf16x8*)(so + p * OSB + cc);
        }
        __syncthreads();
    } else if (MODE == 1) {
        bf16_t* srh = (bf16_t*)smem;                         // [128][72] bf16
        float*  sz  = (float*)(smem + 128 * 72 * 2);         // [128][68] f32
#pragma unroll
        for (int mi = 0; mi < MT_W; ++mi) {
            const int mt = mt0 + mi;
            const int lpx0 = (mt >> 2) * 64 + (mt & 3) * 16 + kg * 4;
#pragma unroll
            for (int ni = 0; ni < NT_W; ++ni) {
                const int co = (nt0 + ni) * 16 + l15;
#pragma unroll
                for (int reg = 0; reg < 4; ++reg) {
                    const int lpx = lpx0 + reg;
                    float s = fsigmoid(acc[mi][ni][reg]);
                    if (co < HID) {
                        float hv = (float)np.Hb[(pixbase + lpx) * HID + co];
                        srh[lpx * 72 + co] = (bf16_t)(s * hv);   // rh
                    } else {
                        sz[lpx * 68 + (co - HID)] = s;           // z
                    }
                }
            }
        }
        __syncthreads();
        for (int i = tid; i < 128 * 8; i += 256) {
            const int p = i >> 3, cc = (i & 7) * 8;
            *(bf16x8*)(np.outB + (pixbase + p) * HID + cc) =
                *(const bf16x8*)(srh + p * 72 + cc);
        }
        for (int i = tid; i < 128 * 16; i += 256) {
            const int p = i >> 4, cc = (i & 15) * 4;
            *(f32x4*)(np.outF + (pixbase + p) * HID + cc) =
                *(const f32x4*)(sz + p * 68 + cc);
        }
        __syncthreads();
    } else {
        float*  shf = (float*)smem;                          // [128][68] f32
        bf16_t* shb = (bf16_t*)(smem + 128 * 68 * 4);        // [128][72] bf16
#pragma unroll
        for (int mi = 0; mi < MT_W; ++mi) {
            const int mt = mt0 + mi;
            const int lpx0 = (mt >> 2) * 64 + (mt & 3) * 16 + kg * 4;
#pragma unroll
            for (int ni = 0; ni < NT_W; ++ni) {
                const int co = (nt0 + ni) * 16 + l15;
#pragma unroll
                for (int reg = 0; reg < 4; ++reg) {
                    const int lpx = lpx0 + reg;
                    float cd = ftanh(acc[mi][ni][reg]);
                    float z  = np.Zf[(pixbase + lpx) * HID + co];
                    float ho = np.Hf[(pixbase + lpx) * HID + co];
                    float hn = z * ho + (1.0f - z) * cd;
                    shf[lpx * 68 + co] = hn;
                    shb[lpx * 72 + co] = (bf16_t)hn;
                }
            }
        }
        __syncthreads();
        for (int i = tid; i < 128 * 16; i += 256) {
            const int p = i >> 4, cc = (i & 15) * 4;
            *(f32x4*)(np.outF + (pixbase + p) * HID + cc) =
                *(const f32x4*)(shf + p * 68 + cc);
        }
        for (int i = tid; i < 128 * 8; i += 256) {
            const int p = i >> 3, cc = (i & 7) * 8;
            *(bf16x8*)(np.outB + (pixbase + p) * HID + cc) =
                *(const bf16x8*)(shb + p * 72 + cc);
        }
        __syncthreads();
    }
}

// ---------------------------------------------------------------------------
// Fallback standalone kernels (R12 path)
// ---------------------------------------------------------------------------
template <int CIN0, int CIN1, int COUT, int MODE, int MINW>
__global__ __launch_bounds__(256, MINW) void mconv(NPs P)
{
    constexpr int CIN  = CIN0 + CIN1;
    constexpr int PSB  = CIN * 2 + 8;
    constexpr int ASMEM = 4 * 66 * PSB;
    constexpr int OSB   = COUT + 8;
    constexpr int OSMEM = (MODE == 0) ? 128 * OSB * 2 : 128 * 68 * 4 + 128 * 72 * 2;
    constexpr int SMEM  = (ASMEM > OSMEM) ? ASMEM : OSMEM;
    __shared__ __align__(16) char smem[SMEM];
    conv_stage<CIN0, CIN1, COUT, MODE>(smem, P.n[blockIdx.y], blockIdx.x, threadIdx.x);
}

// ---------------------------------------------------------------------------
// Persistent cooperative kernel: whole recurrence + output transpose.
// grid = 512 blocks (2/CU guaranteed: 2 x 53,248 B LDS = 106 KB <= 160 KB).
// Stride loop over <=768 virtual blocks per stage; grid.sync() between stages.
// ---------------------------------------------------------------------------
struct GParams {
    const bf16_t* xb;
    bf16_t* p; bf16_t* bu; bf16_t* rh; float* zb;
    float*  hF[3][2];
    bf16_t* hB[3][2];
    const bf16_t* WpProj[3]; const float* bProj[3];
    const bf16_t* WpInt[3];  const float* bInt[3];
    const bf16_t* WpG[3];    const float* bG[3];
    const bf16_t* WpC[3];    const float* bC[3];
    float* out;
};

__device__ __forceinline__ int hpar(int t, int n) {
    int c = t - n;
    c = (c < 0) ? 0 : ((c > 8) ? 8 : c);
    return c & 1;
}

__global__ __launch_bounds__(256, 2) void gru_persist(GParams P) {
    __shared__ __align__(16) char smem[53248];
    cooperative_groups::grid_group grid = cooperative_groups::this_grid();
    const int tid = threadIdx.x;
    const long PSZ  = (long)PIXN * 32;
    const long RHSZ = (long)PIXN * HID;
    const long ZSZ  = (long)PIXN * HID;

    for (int t = 0; t < PT; ++t) {
        const int nLo = (t > 7) ? (t - 7) : 0;
        const int nHi = (t < 2) ? t : 2;
        const int total = 256 * (nHi - nLo + 1);

        // ---- proj (CIN=64 -> 32) ----
        for (int vb = blockIdx.x; vb < total; vb += gridDim.x) {
            const int n = nLo + (vb >> 8);
            NP np{};
            if (n == 0) {
                np.A0 = P.xb + (long)t * PIXN * 64;
                np.Wp = P.WpProj[0]; np.bias = P.bProj[0];
            } else {
                np.A0 = P.hB[n - 1][hpar(t, n - 1)];
                np.Wp = P.WpProj[n]; np.bias = P.bProj[n];
            }
            np.outB = P.p + (long)n * PSZ;
            conv_stage<64, 0, 32, 0>(smem, np, vb & 255, tid);
        }
        grid.sync();
        // ---- integrator (32 -> 32) ----
        for (int vb = blockIdx.x; vb < total; vb += gridDim.x) {
            const int n = nLo + (vb >> 8);
            NP np{};
            np.A0 = P.p + (long)n * PSZ;
            np.Wp = P.WpInt[n]; np.bias = P.bInt[n];
            np.outB = P.bu + (long)n * PSZ;
            conv_stage<32, 0, 32, 0>(smem, np, vb & 255, tid);
        }
        grid.sync();
        // ---- gates (96 -> 128): rh bf16 + z f32 ----
        for (int vb = blockIdx.x; vb < total; vb += gridDim.x) {
            const int n = nLo + (vb >> 8);
            const int cur = hpar(t, n);
            NP np{};
            np.A0 = P.bu + (long)n * PSZ;
            np.A1 = P.hB[n][cur]; np.Hb = P.hB[n][cur];
            np.Wp = P.WpG[n]; np.bias = P.bG[n];
            np.outB = P.rh + (long)n * RHSZ;
            np.outF = P.zb + (long)n * ZSZ;
            conv_stage<32, 64, 128, 1>(smem, np, vb & 255, tid);
        }
        grid.sync();
        // ---- cand (96 -> 64) + GRU update ----
        for (int vb = blockIdx.x; vb < total; vb += gridDim.x) {
            const int n = nLo + (vb >> 8);
            const int cur = hpar(t, n);
            NP np{};
            np.A0 = P.bu + (long)n * PSZ;
            np.A1 = P.rh + (long)n * RHSZ;
            np.Zf = P.zb + (long)n * ZSZ;
            np.Hf = P.hF[n][cur];
            np.Wp = P.WpC[n]; np.bias = P.bC[n];
            np.outB = P.hB[n][cur ^ 1];
            np.outF = P.hF[n][cur ^ 1];
            conv_stage<32, 64, 64, 2>(smem, np, vb & 255, tid);
        }
        grid.sync();
    }

    // ---- output: hF[2][0] (8 updates -> parity 0) NHWC -> NCHW fp32 ----
    const float* hf = P.hF[2][0];
    for (long idx = (long)blockIdx.x * 256 + tid; idx < (long)8 * 64 * 64 * 64;
         idx += (long)gridDim.x * 256) {
        int xx = idx & 63;
        int y  = (idx >> 6) & 63;
        int c  = (idx >> 12) & 63;
        int b  = idx >> 18;
        P.out[idx] = hf[((((long)b * 64 + y) * 64 + xx) * 64) + c];
    }
}

// ---------------------------------------------------------------------------
extern "C" void kernel_launch(void* const* d_in, const int* in_sizes, int n_in,
                              void* d_out, int out_size, void* d_ws, size_t ws_size,
                              hipStream_t stream) {
    const float* x    = (const float*)d_in[0];
    const float* Win0 = (const float*)d_in[1];
    const float* bin0 = (const float*)d_in[2];
    const float* We10 = (const float*)d_in[3];
    const float* be10 = (const float*)d_in[4];
    const float* We21 = (const float*)d_in[5];
    const float* be21 = (const float*)d_in[6];
    const float* Wint[3] = {(const float*)d_in[7],  (const float*)d_in[13], (const float*)d_in[19]};
    const float* bint[3] = {(const float*)d_in[8],  (const float*)d_in[14], (const float*)d_in[20]};
    const float* Wg[3]   = {(const float*)d_in[9],  (const float*)d_in[15], (const float*)d_in[21]};
    const float* bg[3]   = {(const float*)d_in[10], (const float*)d_in[16], (const float*)d_in[22]};
    const float* Wc[3]   = {(const float*)d_in[11], (const float*)d_in[17], (const float*)d_in[23]};
    const float* bc[3]   = {(const float*)d_in[12], (const float*)d_in[18], (const float*)d_in[24]};
    (void)in_sizes; (void)n_in; (void)out_size; (void)ws_size;

    const long PIX  = (long)PIXN;
    const size_t HFSZ = (size_t)PIX * HID * 4;    // 8 MB
    const size_t HBSZ = (size_t)PIX * HID * 2;    // 4 MB
    const long PSZ  = PIX * 32;
    const long RHSZ = PIX * HID;
    const long ZSZ  = PIX * HID;

    char* wsb = (char*)d_ws;
    size_t off = 0;
    auto alloc = [&](size_t bytes) -> char* {
        char* q = wsb + off;
        off = (off + bytes + 255) & ~(size_t)255;
        return q;
    };

    // zero-group (contiguous): parity-0 h buffers
    float*  hF0[3]; bf16_t* hB0[3];
    hF0[0] = (float*)alloc(HFSZ); hF0[1] = (float*)alloc(HFSZ); hF0[2] = (float*)alloc(HFSZ);
    hB0[0] = (bf16_t*)alloc(HBSZ); hB0[1] = (bf16_t*)alloc(HBSZ); hB0[2] = (bf16_t*)alloc(HBSZ);
    const size_t zeroBytes = 3 * HFSZ + 3 * HBSZ;
    float*  hF1[3]; bf16_t* hB1[3];
    hF1[0] = (float*)alloc(HFSZ); hF1[1] = (float*)alloc(HFSZ); hF1[2] = (float*)alloc(HFSZ);
    hB1[0] = (bf16_t*)alloc(HBSZ); hB1[1] = (bf16_t*)alloc(HBSZ); hB1[2] = (bf16_t*)alloc(HBSZ);
    bf16_t* xb = (bf16_t*)alloc((size_t)TSEQ * PIX * 64 * 2);
    bf16_t* p  = (bf16_t*)alloc((size_t)3 * PSZ * 2);
    bf16_t* bu = (bf16_t*)alloc((size_t)3 * PSZ * 2);
    bf16_t* rh = (bf16_t*)alloc((size_t)3 * RHSZ * 2);
    float*  zb = (float*) alloc((size_t)3 * ZSZ * 4);
    bf16_t* WpIn0 = (bf16_t*)alloc((size_t)18432 * 2);
    bf16_t* WpE10 = (bf16_t*)alloc((size_t)18432 * 2);
    bf16_t* WpE21 = (bf16_t*)alloc((size_t)18432 * 2);
    bf16_t* WpInt[3], *WpG[3], *WpC[3];
    for (int n = 0; n < 3; ++n) WpInt[n] = (bf16_t*)alloc((size_t)9216 * 2);
    for (int n = 0; n < 3; ++n) WpG[n]   = (bf16_t*)alloc((size_t)110592 * 2);
    for (int n = 0; n < 3; ++n) WpC[n]   = (bf16_t*)alloc((size_t)55296 * 2);

    hipMemsetAsync(hF0[0], 0, zeroBytes, stream);

    // ---- weight packing + x conversion ----
    PackArgs PA{};
    int beg = 0;
    auto seg = [&](int i, const float* src, bf16_t* dst, int Cout, int CinPad, int CinReal) {
        PA.s[i] = {src, dst, Cout / 16, CinPad / 32, CinReal, beg};
        beg += 9 * (CinPad / 32) * (Cout / 16) * 512;
    };
    seg(0, Win0, WpIn0, 32, 64, 3);
    seg(1, We10, WpE10, 32, 64, 64);
    seg(2, We21, WpE21, 32, 64, 64);
    for (int n = 0; n < 3; ++n) seg(3 + n, Wint[n], WpInt[n], 32, 32, 32);
    for (int n = 0; n < 3; ++n) seg(6 + n, Wg[n],   WpG[n],   128, 96, 96);
    for (int n = 0; n < 3; ++n) seg(9 + n, Wc[n],   WpC[n],   64, 96, 96);
    PA.total = beg;
    wpack_all<<<(PA.total + 255) / 256, 256, 0, stream>>>(PA);
    xcvt_k<<<(8 * 8 * 64 * 64 * 64 + 255) / 256, 256, 0, stream>>>(x, xb);

    // ---- try persistent cooperative path ----
    GParams GP{};
    GP.xb = xb;
    GP.p = p; GP.bu = bu; GP.rh = rh; GP.zb = zb;
    for (int n = 0; n < 3; ++n) {
        GP.hF[n][0] = hF0[n]; GP.hF[n][1] = hF1[n];
        GP.hB[n][0] = hB0[n]; GP.hB[n][1] = hB1[n];
    }
    GP.WpProj[0] = WpIn0; GP.WpProj[1] = WpE10; GP.WpProj[2] = WpE21;
    GP.bProj[0]  = bin0;  GP.bProj[1]  = be10;  GP.bProj[2]  = be21;
    for (int n = 0; n < 3; ++n) {
        GP.WpInt[n] = WpInt[n]; GP.bInt[n] = bint[n];
        GP.WpG[n]   = WpG[n];   GP.bG[n]   = bg[n];
        GP.WpC[n]   = WpC[n];   GP.bC[n]   = bc[n];
    }
    GP.out = (float*)d_out;

    void* args[] = { &GP };
    hipError_t cerr = hipLaunchCooperativeKernel(
        reinterpret_cast<void*>(gru_persist), dim3(512), dim3(256), args, 0, stream);
    if (cerr == hipSuccess) return;
    (void)hipGetLastError();   // clear sticky error; fall back to multi-dispatch

    // ---- fallback: R12 multi-dispatch path (proven, 764 us) ----
    float*  hFc[3] = {hF0[0], hF0[1], hF0[2]};
    float*  hFn[3] = {hF1[0], hF1[1], hF1[2]};
    bf16_t* hBc[3] = {hB0[0], hB0[1], hB0[2]};
    bf16_t* hBn[3] = {hB1[0], hB1[1], hB1[2]};
    const bf16_t* WpE[2] = {WpE10, WpE21};
    const float*  beE[2] = {be10, be21};

    const dim3 T(256);
    const int GX = BATCH * (HH / 2);   // 256

    for (int t = 0; t < PT; ++t) {
        const int nLo = (t > 7) ? (t - 7) : 0;
        const int nHi = (t < 2) ? t : 2;
        const int nAct = nHi - nLo + 1;
        {
            NPs P{};
            for (int i = 0; i < nAct; ++i) {
                int n = nLo + i;
                if (n == 0) {
                    P.n[i].A0 = xb + (long)t * PIX * 64;
                    P.n[i].Wp = WpIn0; P.n[i].bias = bin0;
                } else {
                    P.n[i].A0 = hBc[n - 1];
                    P.n[i].Wp = WpE[n - 1]; P.n[i].bias = beE[n - 1];
                }
                P.n[i].outB = p + (long)n * PSZ;
            }
            mconv<64, 0, 32, 0, 3><<<dim3(GX, nAct), T, 0, stream>>>(P);
        }
        {
            NPs P{};
            for (int i = 0; i < nAct; ++i) {
                int n = nLo + i;
                P.n[i].A0 = p + (long)n * PSZ;
                P.n[i].Wp = WpInt[n]; P.n[i].bias = bint[n];
                P.n[i].outB = bu + (long)n * PSZ;
            }
            mconv<32, 0, 32, 0, 4><<<dim3(GX, nAct), T, 0, stream>>>(P);
        }
        {
            NPs P{};
            for (int i = 0; i < nAct; ++i) {
                int n = nLo + i;
                P.n[i].A0 = bu + (long)n * PSZ; P.n[i].A1 = hBc[n]; P.n[i].Hb = hBc[n];
                P.n[i].Wp = WpG[n]; P.n[i].bias = bg[n];
                P.n[i].outB = rh + (long)n * RHSZ; P.n[i].outF = zb + (long)n * ZSZ;
            }
            mconv<32, 64, 128, 1, 3><<<dim3(GX, nAct), T, 0, stream>>>(P);
        }
        {
            NPs P{};
            for (int i = 0; i < nAct; ++i) {
                int n = nLo + i;
                P.n[i].A0 = bu + (long)n * PSZ; P.n[i].A1 = rh + (long)n * RHSZ;
                P.n[i].Zf = zb + (long)n * ZSZ; P.n[i].Hf = hFc[n];
                P.n[i].Wp = WpC[n]; P.n[i].bias = bc[n];
                P.n[i].outB = hBn[n]; P.n[i].outF = hFn[n];
            }
            mconv<32, 64, 64, 2, 3><<<dim3(GX, nAct), T, 0, stream>>>(P);
        }
        for (int n = nLo; n <= nHi; ++n) {
            float* tf = hFc[n]; hFc[n] = hFn[n]; hFn[n] = tf;
            bf16_t* tb = hBc[n]; hBc[n] = hBn[n]; hBn[n] = tb;
        }
    }

    hout_k<<<(8 * 64 * 64 * 64 + 255) / 256, 256, 0, stream>>>(hFc[2], (float*)d_out);
}

// Round 14
// 762.113 us; speedup vs baseline: 6.0145x; 6.0145x over previous
//
#include <hip/hip_runtime.h>
#include <hip/hip_bf16.h>

#define BATCH 8
#define TSEQ 8
#define HH 64
#define WW 64
#define HID 64
#define PT 10   // T + NUM_NODE - 1
#define PIXN 32768   // BATCH*HH*WW

typedef __bf16 bf16_t;
typedef __bf16 bf16x8 __attribute__((ext_vector_type(8)));
typedef float  f32x4  __attribute__((ext_vector_type(4)));

__device__ __forceinline__ float fsigmoid(float v) {
    float e = __builtin_amdgcn_exp2f(-1.4426950408889634f * v);
    return __builtin_amdgcn_rcpf(1.0f + e);
}
__device__ __forceinline__ float ftanh(float v) {
    float e = __builtin_amdgcn_exp2f(2.8853900817779268f * v);   // e^(2v)
    return 1.0f - 2.0f * __builtin_amdgcn_rcpf(1.0f + e);
}

// ---------------------------------------------------------------------------
// Weight pack for 16x16x32 MFMA B-fragments (R10):
//   dst[((chunk*NT16 + nt)*64 + lane)*8 + j],  chunk = tap*KC + kc  (KC=CinPad/32)
//     = w[co = nt*16 + (lane&15)][ci = kc*32 + (lane>>4)*8 + j][tap]
// ---------------------------------------------------------------------------
struct PackSeg { const float* src; bf16_t* dst; int NT16; int KC; int CinReal; int begin; };
struct PackArgs { PackSeg s[12]; int total; };

__global__ void wpack_all(PackArgs P) {
    int idx = blockIdx.x * 256 + threadIdx.x;
    if (idx >= P.total) return;
    int si = 0;
#pragma unroll
    for (int i = 1; i < 12; ++i) if (idx >= P.s[i].begin) si = i;
    PackSeg sg = P.s[si];
    int l = idx - sg.begin;
    int j    = l & 7;
    int lane = (l >> 3) & 63;
    int rest = l >> 9;
    int nt   = rest % sg.NT16;
    int chunk = rest / sg.NT16;
    int kc  = chunk % sg.KC;
    int tap = chunk / sg.KC;
    int co = nt * 16 + (lane & 15);
    int ci = kc * 32 + (lane >> 4) * 8 + j;
    float v = (ci < sg.CinReal) ? sg.src[((long)co * sg.CinReal + ci) * 9 + tap] : 0.0f;
    sg.dst[l] = (bf16_t)v;
}

// x (B,T,3,H,W) fp32 -> xb [t][b][y][x][64] bf16 (channels 3..63 zero)
__global__ void xcvt_k(const float* __restrict__ x, bf16_t* __restrict__ xb) {
    int idx = blockIdx.x * 256 + threadIdx.x;
    if (idx >= 8 * 8 * 64 * 64 * 64) return;
    int c  = idx & 63;
    int xx = (idx >> 6) & 63;
    int y  = (idx >> 12) & 63;
    int b  = (idx >> 18) & 7;
    int t  = idx >> 21;
    float v = 0.0f;
    if (c < 3) v = x[((((long)b * TSEQ + t) * 3 + c) * 64 + y) * 64 + xx];
    xb[idx] = (bf16_t)v;
}

// ---------------------------------------------------------------------------
// Fused proj+int kernel (halo-recompute, bit-identical math):
// Phase A: stage x 6 rows x 66 px x 64ch (PSB 136).
// Phase B: proj conv -> p on 4 rows (2 output rows + 1 halo each side),
//          bf16-rounded into LDS p-region (PSB 72), borders zeroed (exact
//          zero-pad semantics of the intermediate tensor).
// Phase C: int conv on p -> bu for 2 rows; LDS-bounced coalesced store.
// One dispatch replaces the proj+int pair (two serial boundaries -> one).
// ---------------------------------------------------------------------------
struct PJ {
    const bf16_t* X;        // NHWC 64ch input (x or h)
    const bf16_t* Wpj;      // packed proj weights (18 chunks, NT16=2)
    const float*  bpj;
    const bf16_t* Wit;      // packed int weights (9 chunks, NT16=2)
    const float*  bit;
    bf16_t* outB;           // bu NHWC 32ch
};
struct PJs { PJ u[8]; };

__global__ __launch_bounds__(256, 2) void projint_k(PJs P) {
    constexpr int PSBX = 136;                 // 64ch*2 + 8
    constexpr int PSBP = 72;                  // 32ch*2 + 8
    constexpr int POFF = 6 * 66 * PSBX;       // 53,856
    __shared__ __align__(16) char smem[6 * 66 * PSBX + 4 * 66 * PSBP];  // 72,864

    const PJ u = P.u[blockIdx.y];
    const int tid = threadIdx.x, lane = tid & 63, w = tid >> 6;
    const int b = blockIdx.x & 7, y0 = (blockIdx.x >> 3) * 2;
    const int l15 = lane & 15, kg = lane >> 4;

    // ring prologue (proj weights)
    const bf16_t* wpp = u.Wpj + (size_t)(w & 1) * 512 + (size_t)lane * 8;
    bf16x8 ring[4];
#pragma unroll
    for (int i = 0; i < 4; ++i) ring[i] = *(const bf16x8*)(wpp + (size_t)i * 1024);

    // stage x: 6 rows (y0-2 .. y0+3) x 66 px x 64 ch
    for (int c = tid; c < 6 * 66 * 8; c += 256) {
        int ry = c / (66 * 8);
        int r  = c - ry * (66 * 8);
        int px = r >> 3, c2 = r & 7;
        int gy = y0 + ry - 2, gx = px - 1;
        bf16x8 v = {};
        if ((unsigned)gy < 64u && (unsigned)gx < 64u)
            v = *(const bf16x8*)(u.X + (((long)b * 64 + gy) * 64 + gx) * 64 + c2 * 8);
        *(bf16x8*)(smem + (ry * 66 + px) * PSBX + c2 * 16) = v;
    }
    // zero p halo cols (rows 0..3, cols {0,65}, 4 x 8ch chunks)
    if (tid < 32) {
        int row = tid >> 3;
        int col = ((tid >> 2) & 1) ? 65 : 0;
        int chk = tid & 3;
        *(bf16x8*)(smem + POFF + (row * 66 + col) * PSBP + chk * 16) = (bf16x8){};
    }
    // zero p out-of-image rows (row 0 iff y0==0; row 3 iff y0==62)
    if (y0 == 0)
        for (int i = tid; i < 66 * 4; i += 256)
            *(bf16x8*)(smem + POFF + (0 * 66 + (i >> 2)) * PSBP + (i & 3) * 16) = (bf16x8){};
    if (y0 == 62)
        for (int i = tid; i < 66 * 4; i += 256)
            *(bf16x8*)(smem + POFF + (3 * 66 + (i >> 2)) * PSBP + (i & 3) * 16) = (bf16x8){};
    __syncthreads();

    // ---- phase B: proj conv, 16 m-tiles (4 p-rows x 64 px) ----
    const int ntp = w & 1, mtb = (w >> 1) * 8;
    f32x4 pacc[8];
    {
        float bv = u.bpj[ntp * 16 + l15];
#pragma unroll
        for (int mi = 0; mi < 8; ++mi) pacc[mi] = (f32x4){bv, bv, bv, bv};
    }
#pragma unroll
    for (int ch = 0; ch < 18; ++ch) {
        const int tap = ch >> 1, kc = ch & 1;
        const int ky = tap / 3, kx = tap % 3;
        bf16x8 bcur = ring[ch & 3];
        if (ch + 4 < 18) ring[ch & 3] = *(const bf16x8*)(wpp + (size_t)(ch + 4) * 1024);
#pragma unroll
        for (int mi = 0; mi < 8; ++mi) {
            const int mt = mtb + mi;
            const int prow = mt >> 2, xseg = mt & 3;
            const int addr = ((prow + ky) * 66 + xseg * 16 + l15 + kx) * PSBX
                           + kg * 16 + kc * 64;
            bf16x8 a = *(const bf16x8*)(smem + addr);
            pacc[mi] = __builtin_amdgcn_mfma_f32_16x16x32_bf16(a, bcur, pacc[mi], 0, 0, 0);
        }
    }
    // int-weight ring prologue (hide latency under p-writes)
    const bf16_t* wpi = u.Wit + (size_t)(w & 1) * 512 + (size_t)lane * 8;
    bf16x8 ring2[4];
#pragma unroll
    for (int i = 0; i < 4; ++i) ring2[i] = *(const bf16x8*)(wpi + (size_t)i * 1024);
    // write p (bf16) into LDS p-region; skip out-of-image rows (left zeroed)
#pragma unroll
    for (int mi = 0; mi < 8; ++mi) {
        const int mt = mtb + mi;
        const int prow = mt >> 2, xseg = mt & 3;
        const int gyp = y0 - 1 + prow;
        if (gyp >= 0 && gyp < 64) {
            const int co = ntp * 16 + l15;
#pragma unroll
            for (int reg = 0; reg < 4; ++reg) {
                const int pxi = xseg * 16 + kg * 4 + reg;
                *(bf16_t*)(smem + POFF + (prow * 66 + pxi + 1) * PSBP + co * 2) =
                    (bf16_t)pacc[mi][reg];
            }
        }
    }
    __syncthreads();

    // ---- phase C: int conv on p, 8 m-tiles (2 rows) ----
    const int nti = w & 1, mtb2 = (w >> 1) * 4;
    f32x4 iacc[4];
    {
        float bv = u.bit[nti * 16 + l15];
#pragma unroll
        for (int mi = 0; mi < 4; ++mi) iacc[mi] = (f32x4){bv, bv, bv, bv};
    }
#pragma unroll
    for (int ch = 0; ch < 9; ++ch) {
        const int ky = ch / 3, kx = ch % 3;
        bf16x8 bcur = ring2[ch & 3];
        if (ch + 4 < 9) ring2[ch & 3] = *(const bf16x8*)(wpi + (size_t)(ch + 4) * 1024);
#pragma unroll
        for (int mi = 0; mi < 4; ++mi) {
            const int mt = mtb2 + mi;
            const int r2 = mt >> 2, xseg = mt & 3;
            const int addr = POFF + ((r2 + ky) * 66 + xseg * 16 + l15 + kx) * PSBP + kg * 16;
            bf16x8 a = *(const bf16x8*)(smem + addr);
            iacc[mi] = __builtin_amdgcn_mfma_f32_16x16x32_bf16(a, bcur, iacc[mi], 0, 0, 0);
        }
    }
    // ---- epilogue: bounce bu via x-region, coalesced store ----
    bf16_t* so = (bf16_t*)smem;                 // [128][40]
#pragma unroll
    for (int mi = 0; mi < 4; ++mi) {
        const int mt = mtb2 + mi;
        const int lpx0 = (mt >> 2) * 64 + (mt & 3) * 16 + kg * 4;
        const int co = nti * 16 + l15;
#pragma unroll
        for (int reg = 0; reg < 4; ++reg)
            so[(lpx0 + reg) * 40 + co] = (bf16_t)iacc[mi][reg];
    }
    __syncthreads();
    const long pixbase = ((long)b * 64 + y0) * 64;
    for (int i = tid; i < 128 * 4; i += 256) {
        const int p = i >> 2, cc = (i & 3) * 8;
        *(bf16x8*)(u.outB + (pixbase + p) * 32 + cc) = *(const bf16x8*)(so + p * 40 + cc);
    }
}

// ---------------------------------------------------------------------------
// Gates / cand conv (R12 body). MODE 1: gates -> rh bf16 + z f32.
// MODE 2: cand -> h fp32 + h bf16. MODE 3: cand final -> NCHW fp32 d_out.
// ---------------------------------------------------------------------------
struct NP {
    const bf16_t* A0;
    const bf16_t* A1;
    const float*  Zf;
    const float*  Hf;
    const bf16_t* Hb;
    const bf16_t* Wp;
    const float*  bias;
    bf16_t* outB;
    float*  outF;
};
struct NPs { NP n[3]; };

template <int CIN0, int CIN1, int COUT, int MODE, int MINW>
__global__ __launch_bounds__(256, MINW) void mconv(NPs P)
{
    constexpr int CIN  = CIN0 + CIN1;
    constexpr int NT16 = COUT / 16;
    constexpr int NCH  = CIN / 8;
    constexpr int KC   = CIN / 32;
    constexpr int NCHUNK = 9 * KC;
    constexpr int PSB  = CIN * 2 + 8;
    constexpr int NT_W = (NT16 > 4) ? NT16 / 4 : 1;
    constexpr int NW_N = NT16 / NT_W;
    constexpr int NW_M = 4 / NW_N;
    constexpr int MT_W = 8 / NW_M;
    constexpr int PF   = 4;
    constexpr int ASMEM = 4 * 66 * PSB;
    constexpr int OSMEM = (MODE == 1 || MODE == 2) ? 128 * 68 * 4 + 128 * 72 * 2
                                                   : 128 * 69 * 4;
    constexpr int SMEM  = (ASMEM > OSMEM) ? ASMEM : OSMEM;

    const NP np   = P.n[blockIdx.y];
    const int tid  = threadIdx.x;
    const int lane = tid & 63;
    const int w    = tid >> 6;
    const int b  = blockIdx.x & 7;
    const int y0 = (blockIdx.x >> 3) * 2;

    __shared__ __align__(16) char smem[SMEM];

    const int nt0 = (w % NW_N) * NT_W;
    const int mt0 = (w / NW_N) * MT_W;
    const int l15 = lane & 15;
    const int kg  = lane >> 4;

    const bf16_t* wp0 = np.Wp + (size_t)nt0 * 512 + (size_t)lane * 8;
    bf16x8 ring[PF][NT_W];
#pragma unroll
    for (int i = 0; i < PF; ++i)
#pragma unroll
        for (int ni = 0; ni < NT_W; ++ni)
            ring[i][ni] = *(const bf16x8*)(wp0 + (size_t)i * (NT16 * 512) + ni * 512);

    for (int c = tid; c < 4 * 66 * NCH; c += 256) {
        int ry = c / (66 * NCH);
        int r  = c - ry * 66 * NCH;
        int px = r / NCH;
        int c2 = r - px * NCH;
        int gy = y0 + ry - 1, gx = px - 1;
        bf16x8 v = {};
        if ((unsigned)gy < 64u && (unsigned)gx < 64u) {
            long pix = ((long)b * 64 + gy) * 64 + gx;
            int ci = c2 * 8;
            if (CIN1 == 0 || ci < CIN0) v = *(const bf16x8*)(np.A0 + pix * CIN0 + ci);
            else                        v = *(const bf16x8*)(np.A1 + pix * CIN1 + (ci - CIN0));
        }
        *(bf16x8*)(smem + (ry * 66 + px) * PSB + c2 * 16) = v;
    }
    __syncthreads();

    int ab[3];
#pragma unroll
    for (int kx = 0; kx < 3; ++kx)
        ab[kx] = (l15 + kx) * PSB + kg * 16;

    f32x4 acc[MT_W][NT_W];
#pragma unroll
    for (int mi = 0; mi < MT_W; ++mi)
#pragma unroll
        for (int ni = 0; ni < NT_W; ++ni) {
            float bv = np.bias[(nt0 + ni) * 16 + l15];
            acc[mi][ni] = (f32x4){bv, bv, bv, bv};
        }

#pragma unroll
    for (int ch = 0; ch < NCHUNK; ++ch) {
        const int tap = ch / KC, kc = ch % KC;
        const int ky = tap / 3, kx = tap % 3;
        bf16x8 bcur[NT_W];
#pragma unroll
        for (int ni = 0; ni < NT_W; ++ni) bcur[ni] = ring[ch % PF][ni];
        if (ch + PF < NCHUNK) {
#pragma unroll
            for (int ni = 0; ni < NT_W; ++ni)
                ring[ch % PF][ni] =
                    *(const bf16x8*)(wp0 + (size_t)(ch + PF) * (NT16 * 512) + ni * 512);
        }
#pragma unroll
        for (int mi = 0; mi < MT_W; ++mi) {
            const int mt = mt0 + mi;
            const int row = mt >> 2, xseg = mt & 3;
            const int imm = (row + ky) * (66 * PSB) + xseg * (16 * PSB) + kc * 64;
            bf16x8 a = *(const bf16x8*)(smem + ab[kx] + imm);
#pragma unroll
            for (int ni = 0; ni < NT_W; ++ni)
                acc[mi][ni] = __builtin_amdgcn_mfma_f32_16x16x32_bf16(
                    a, bcur[ni], acc[mi][ni], 0, 0, 0);
        }
    }

    __syncthreads();
    const long pixbase = ((long)b * 64 + y0) * 64;

    if (MODE == 1) {
        bf16_t* srh = (bf16_t*)smem;                         // [128][72] bf16
        float*  sz  = (float*)(smem + 128 * 72 * 2);         // [128][68] f32
#pragma unroll
        for (int mi = 0; mi < MT_W; ++mi) {
            const int mt = mt0 + mi;
            const int lpx0 = (mt >> 2) * 64 + (mt & 3) * 16 + kg * 4;
#pragma unroll
            for (int ni = 0; ni < NT_W; ++ni) {
                const int co = (nt0 + ni) * 16 + l15;
#pragma unroll
                for (int reg = 0; reg < 4; ++reg) {
                    const int lpx = lpx0 + reg;
                    float s = fsigmoid(acc[mi][ni][reg]);
                    if (co < HID) {
                        float hv = (float)np.Hb[(pixbase + lpx) * HID + co];
                        srh[lpx * 72 + co] = (bf16_t)(s * hv);   // rh
                    } else {
                        sz[lpx * 68 + (co - HID)] = s;           // z
                    }
                }
            }
        }
        __syncthreads();
        for (int i = tid; i < 128 * 8; i += 256) {
            const int p = i >> 3, cc = (i & 7) * 8;
            *(bf16x8*)(np.outB + (pixbase + p) * HID + cc) =
                *(const bf16x8*)(srh + p * 72 + cc);
        }
        for (int i = tid; i < 128 * 16; i += 256) {
            const int p = i >> 4, cc = (i & 15) * 4;
            *(f32x4*)(np.outF + (pixbase + p) * HID + cc) =
                *(const f32x4*)(sz + p * 68 + cc);
        }
    } else if (MODE == 2) {
        float*  shf = (float*)smem;                          // [128][68] f32
        bf16_t* shb = (bf16_t*)(smem + 128 * 68 * 4);        // [128][72] bf16
#pragma unroll
        for (int mi = 0; mi < MT_W; ++mi) {
            const int mt = mt0 + mi;
            const int lpx0 = (mt >> 2) * 64 + (mt & 3) * 16 + kg * 4;
#pragma unroll
            for (int ni = 0; ni < NT_W; ++ni) {
                const int co = (nt0 + ni) * 16 + l15;
#pragma unroll
                for (int reg = 0; reg < 4; ++reg) {
                    const int lpx = lpx0 + reg;
                    float cd = ftanh(acc[mi][ni][reg]);
                    float z  = np.Zf[(pixbase + lpx) * HID + co];
                    float ho = np.Hf[(pixbase + lpx) * HID + co];
                    float hn = z * ho + (1.0f - z) * cd;
                    shf[lpx * 68 + co] = hn;
                    shb[lpx * 72 + co] = (bf16_t)hn;
                }
            }
        }
        __syncthreads();
        for (int i = tid; i < 128 * 16; i += 256) {
            const int p = i >> 4, cc = (i & 15) * 4;
            *(f32x4*)(np.outF + (pixbase + p) * HID + cc) =
                *(const f32x4*)(shf + p * 68 + cc);
        }
        for (int i = tid; i < 128 * 8; i += 256) {
            const int p = i >> 3, cc = (i & 7) * 8;
            *(bf16x8*)(np.outB + (pixbase + p) * HID + cc) =
                *(const bf16x8*)(shb + p * 72 + cc);
        }
    } else {   // MODE 3: final cand -> NCHW fp32 output directly
        float* shf = (float*)smem;                           // [128][69] f32
#pragma unroll
        for (int mi = 0; mi < MT_W; ++mi) {
            const int mt = mt0 + mi;
            const int lpx0 = (mt >> 2) * 64 + (mt & 3) * 16 + kg * 4;
#pragma unroll
            for (int ni = 0; ni < NT_W; ++ni) {
                const int co = (nt0 + ni) * 16 + l15;
#pragma unroll
                for (int reg = 0; reg < 4; ++reg) {
                    const int lpx = lpx0 + reg;
                    float cd = ftanh(acc[mi][ni][reg]);
                    float z  = np.Zf[(pixbase + lpx) * HID + co];
                    float ho = np.Hf[(pixbase + lpx) * HID + co];
                    shf[lpx * 69 + co] = z * ho + (1.0f - z) * cd;
                }
            }
        }
        __syncthreads();
        // NCHW: out[((b*64+co)*64 + y)*64 + x], contiguous in x
        for (int i = tid; i < 128 * 16; i += 256) {
            const int j = i >> 4;               // 0..127: co = j&63, yr = j>>6
            const int cc = (i & 15) * 4;
            const int co = j & 63, yr = j >> 6;
            f32x4 v = { shf[(yr * 64 + cc + 0) * 69 + co],
                        shf[(yr * 64 + cc + 1) * 69 + co],
                        shf[(yr * 64 + cc + 2) * 69 + co],
                        shf[(yr * 64 + cc + 3) * 69 + co] };
            *(f32x4*)(np.outF + (((long)b * 64 + co) * 64 + (y0 + yr)) * 64 + cc) = v;
        }
    }
}

// ---------------------------------------------------------------------------
extern "C" void kernel_launch(void* const* d_in, const int* in_sizes, int n_in,
                              void* d_out, int out_size, void* d_ws, size_t ws_size,
                              hipStream_t stream) {
    const float* x    = (const float*)d_in[0];
    const float* Win0 = (const float*)d_in[1];
    const float* bin0 = (const float*)d_in[2];
    const float* We10 = (const float*)d_in[3];
    const float* be10 = (const float*)d_in[4];
    const float* We21 = (const float*)d_in[5];
    const float* be21 = (const float*)d_in[6];
    const float* Wint[3] = {(const float*)d_in[7],  (const float*)d_in[13], (const float*)d_in[19]};
    const float* bint[3] = {(const float*)d_in[8],  (const float*)d_in[14], (const float*)d_in[20]};
    const float* Wg[3]   = {(const float*)d_in[9],  (const float*)d_in[15], (const float*)d_in[21]};
    const float* bg[3]   = {(const float*)d_in[10], (const float*)d_in[16], (const float*)d_in[22]};
    const float* Wc[3]   = {(const float*)d_in[11], (const float*)d_in[17], (const float*)d_in[23]};
    const float* bc[3]   = {(const float*)d_in[12], (const float*)d_in[18], (const float*)d_in[24]};
    (void)in_sizes; (void)n_in; (void)out_size; (void)ws_size;

    const long PIX  = (long)PIXN;
    const size_t HFSZ = (size_t)PIX * HID * 4;    // 8 MB
    const size_t HBSZ = (size_t)PIX * HID * 2;    // 4 MB
    const long PSZ  = PIX * 32;                   // bu elems per (node|t)
    const long RHSZ = PIX * HID;
    const long ZSZ  = PIX * HID;

    char* wsb = (char*)d_ws;
    size_t off = 0;
    auto alloc = [&](size_t bytes) -> char* {
        char* q = wsb + off;
        off = (off + bytes + 255) & ~(size_t)255;
        return q;
    };

    // zero-group (contiguous)
    float*  hF[6]; bf16_t* hB[6];
    hF[0] = (float*)alloc(HFSZ); hF[1] = (float*)alloc(HFSZ); hF[2] = (float*)alloc(HFSZ);
    hB[0] = (bf16_t*)alloc(HBSZ); hB[1] = (bf16_t*)alloc(HBSZ); hB[2] = (bf16_t*)alloc(HBSZ);
    const size_t zeroBytes = 3 * HFSZ + 3 * HBSZ;
    hF[3] = (float*)alloc(HFSZ); hF[4] = (float*)alloc(HFSZ); hF[5] = (float*)alloc(HFSZ);
    hB[3] = (bf16_t*)alloc(HBSZ); hB[4] = (bf16_t*)alloc(HBSZ); hB[5] = (bf16_t*)alloc(HBSZ);
    bf16_t* xb  = (bf16_t*)alloc((size_t)TSEQ * PIX * 64 * 2);
    bf16_t* bu0 = (bf16_t*)alloc((size_t)TSEQ * PSZ * 2);     // node0 bu, all t
    bf16_t* bu  = (bf16_t*)alloc((size_t)3 * PSZ * 2);        // per-step, nodes 1,2
    bf16_t* rh  = (bf16_t*)alloc((size_t)3 * RHSZ * 2);
    float*  zb  = (float*) alloc((size_t)3 * ZSZ * 4);
    bf16_t* WpIn0 = (bf16_t*)alloc((size_t)18432 * 2);
    bf16_t* WpE10 = (bf16_t*)alloc((size_t)18432 * 2);
    bf16_t* WpE21 = (bf16_t*)alloc((size_t)18432 * 2);
    bf16_t* WpInt[3], *WpG[3], *WpC[3];
    for (int n = 0; n < 3; ++n) WpInt[n] = (bf16_t*)alloc((size_t)9216 * 2);
    for (int n = 0; n < 3; ++n) WpG[n]   = (bf16_t*)alloc((size_t)110592 * 2);
    for (int n = 0; n < 3; ++n) WpC[n]   = (bf16_t*)alloc((size_t)55296 * 2);

    hipMemsetAsync(hF[0], 0, zeroBytes, stream);

    // ---- weight packing + x conversion (upfront) ----
    PackArgs PA{};
    int beg = 0;
    auto seg = [&](int i, const float* src, bf16_t* dst, int Cout, int CinPad, int CinReal) {
        PA.s[i] = {src, dst, Cout / 16, CinPad / 32, CinReal, beg};
        beg += 9 * (CinPad / 32) * (Cout / 16) * 512;
    };
    seg(0, Win0, WpIn0, 32, 64, 3);
    seg(1, We10, WpE10, 32, 64, 64);
    seg(2, We21, WpE21, 32, 64, 64);
    for (int n = 0; n < 3; ++n) seg(3 + n, Wint[n], WpInt[n], 32, 32, 32);
    for (int n = 0; n < 3; ++n) seg(6 + n, Wg[n],   WpG[n],   128, 96, 96);
    for (int n = 0; n < 3; ++n) seg(9 + n, Wc[n],   WpC[n],   64, 96, 96);
    PA.total = beg;
    wpack_all<<<(PA.total + 255) / 256, 256, 0, stream>>>(PA);
    xcvt_k<<<(8 * 8 * 64 * 64 * 64 + 255) / 256, 256, 0, stream>>>(x, xb);

    // ---- node0 bu for ALL 8 timesteps in one dispatch (h-independent) ----
    {
        PJs PJ{};
        for (int t = 0; t < TSEQ; ++t) {
            PJ.u[t].X = xb + (long)t * PIX * 64;
            PJ.u[t].Wpj = WpIn0; PJ.u[t].bpj = bin0;
            PJ.u[t].Wit = WpInt[0]; PJ.u[t].bit = bint[0];
            PJ.u[t].outB = bu0 + (long)t * PSZ;
        }
        projint_k<<<dim3(256, TSEQ), dim3(256), 0, stream>>>(PJ);
    }

    // ---- recurrence: 3 dispatches/step (projint12 -> gates -> cand) ----
    float*  hFc[3] = {hF[0], hF[1], hF[2]};
    float*  hFn[3] = {hF[3], hF[4], hF[5]};
    bf16_t* hBc[3] = {hB[0], hB[1], hB[2]};
    bf16_t* hBn[3] = {hB[3], hB[4], hB[5]};
    const bf16_t* WpE[2] = {WpE10, WpE21};
    const float*  beE[2] = {be10, be21};

    const dim3 T(256);
    const int GX = 256;

    for (int t = 0; t < PT; ++t) {
        const int nLo = (t > 7) ? (t - 7) : 0;
        const int nHi = (t < 2) ? t : 2;
        const int nAct = nHi - nLo + 1;

        // projint for nodes {1,2} active this step
        if (t >= 1) {
            const int lo = (nLo > 1) ? nLo : 1;
            const int cnt = nHi - lo + 1;
            if (cnt > 0) {
                PJs PJ{};
                for (int i = 0; i < cnt; ++i) {
                    int n = lo + i;
                    PJ.u[i].X = hBc[n - 1];
                    PJ.u[i].Wpj = WpE[n - 1]; PJ.u[i].bpj = beE[n - 1];
                    PJ.u[i].Wit = WpInt[n];   PJ.u[i].bit = bint[n];
                    PJ.u[i].outB = bu + (long)n * PSZ;
                }
                projint_k<<<dim3(GX, cnt), T, 0, stream>>>(PJ);
            }
        }
        // gates
        {
            NPs P{};
            for (int i = 0; i < nAct; ++i) {
                int n = nLo + i;
                P.n[i].A0 = (n == 0) ? (bu0 + (long)t * PSZ) : (bu + (long)n * PSZ);
                P.n[i].A1 = hBc[n]; P.n[i].Hb = hBc[n];
                P.n[i].Wp = WpG[n]; P.n[i].bias = bg[n];
                P.n[i].outB = rh + (long)n * RHSZ; P.n[i].outF = zb + (long)n * ZSZ;
            }
            mconv<32, 64, 128, 1, 3><<<dim3(GX, nAct), T, 0, stream>>>(P);
        }
        // cand (+GRU update); final step writes NCHW output directly
        if (t < PT - 1) {
            NPs P{};
            for (int i = 0; i < nAct; ++i) {
                int n = nLo + i;
                P.n[i].A0 = (n == 0) ? (bu0 + (long)t * PSZ) : (bu + (long)n * PSZ);
                P.n[i].A1 = rh + (long)n * RHSZ;
                P.n[i].Zf = zb + (long)n * ZSZ; P.n[i].Hf = hFc[n];
                P.n[i].Wp = WpC[n]; P.n[i].bias = bc[n];
                P.n[i].outB = hBn[n]; P.n[i].outF = hFn[n];
            }
            mconv<32, 64, 64, 2, 3><<<dim3(GX, nAct), T, 0, stream>>>(P);
        } else {
            // t = 9: only node 2 active; write d_out (NCHW fp32) directly
            NPs P{};
            P.n[0].A0 = bu + (long)2 * PSZ;
            P.n[0].A1 = rh + (long)2 * RHSZ;
            P.n[0].Zf = zb + (long)2 * ZSZ; P.n[0].Hf = hFc[2];
            P.n[0].Wp = WpC[2]; P.n[0].bias = bc[2];
            P.n[0].outF = (float*)d_out;
            mconv<32, 64, 64, 3, 3><<<dim3(GX, 1), T, 0, stream>>>(P);
        }
        for (int n = nLo; n <= nHi; ++n) {
            if (t == PT - 1) break;   // no swap needed after final step
            float* tf = hFc[n]; hFc[n] = hFn[n]; hFn[n] = tf;
            bf16_t* tb = hBc[n]; hBc[n] = hBn[n]; hBn[n] = tb;
        }
    }
}